// Round 1
// baseline (1584.576 us; speedup 1.0000x reference)
//
#include <hip/hip_runtime.h>
#include <hip/hip_bf16.h>
#include <cmath>
#include <cstdint>
#include <cstddef>

// Problem constants (B,T,U,D,V) from reference
#define B_ 4
#define T_ 512
#define U_ 128
#define D_ 512
#define V_ 1024
static constexpr size_t OUT_MAIN = (size_t)B_ * T_ * U_ * V_;  // 268435456

typedef __attribute__((ext_vector_type(4))) float f32x4;
typedef __attribute__((ext_vector_type(8))) short s16x8;

__device__ __forceinline__ unsigned short f2bf(float x) {
  union { float f; unsigned u; } v; v.f = x;
  unsigned r = v.u + 0x7fffu + ((v.u >> 16) & 1u);  // RNE
  return (unsigned short)(r >> 16);
}

__device__ __forceinline__ float gelu_erf(float x) {
  return 0.5f * x * (1.0f + erff(x * 0.70710678118654752440f));
}

// tanh-approx gelu (fallback path only; |err vs exact| << 2% threshold)
__device__ __forceinline__ float gelu_tanh(float x) {
  float t = 0.7978845608028654f * x * (1.0f + 0.044715f * x * x);
  t = fminf(fmaxf(t, -15.0f), 15.0f);
  float e = __expf(2.0f * t);
  return 0.5f * x * (1.0f + (e - 1.0f) / (e + 1.0f));
}

__device__ __forceinline__ void gload_lds16(const void* g, void* s) {
  // async global->LDS, 16B/lane; LDS dest = wave-uniform base + lane*16
  __builtin_amdgcn_global_load_lds(
      (const __attribute__((address_space(1))) unsigned int*)g,
      (__attribute__((address_space(3))) unsigned int*)s, 16, 0, 0);
}

// ---- prep: convert W fp32->bf16 (optional) + write lengths as floats ----
__global__ __launch_bounds__(256) void prep_kernel(
    const float* __restrict__ W, const int* __restrict__ sl,
    const int* __restrict__ tl, float* __restrict__ out_tail,
    unsigned short* __restrict__ Wbf, int convert_w) {
  int idx = blockIdx.x * 256 + threadIdx.x;
  if (convert_w) {
    int e = idx * 8;
    if (e < V_ * D_) {
      const float4* p = (const float4*)(W + e);
      float4 a = p[0], b = p[1];
      union { s16x8 v; unsigned short u[8]; } r;
      r.u[0] = f2bf(a.x); r.u[1] = f2bf(a.y); r.u[2] = f2bf(a.z); r.u[3] = f2bf(a.w);
      r.u[4] = f2bf(b.x); r.u[5] = f2bf(b.y); r.u[6] = f2bf(b.z); r.u[7] = f2bf(b.w);
      *(s16x8*)(Wbf + e) = r.v;
    }
  }
  if (blockIdx.x == 0) {
    if (threadIdx.x < B_)
      out_tail[threadIdx.x] = (float)sl[threadIdx.x];
    else if (threadIdx.x < 2 * B_)
      out_tail[threadIdx.x] = (float)tl[threadIdx.x - B_];
  }
}

// ---- stage 1 (two-stage path): joint = bf16(gelu(src+tgt)), 134M elems ----
__global__ __launch_bounds__(256) void gelu_joint_kernel(
    const float* __restrict__ src, const float* __restrict__ tgt,
    unsigned short* __restrict__ joint) {
  size_t idx = (size_t)blockIdx.x * 256 + threadIdx.x;  // 0..16777215
  size_t e = idx * 8;
  int d0 = (int)(e & (D_ - 1));
  size_t row = e >> 9;           // (b*T+t)*U + u
  int bt = (int)(row >> 7);      // b*T + t
  int u = (int)(row & (U_ - 1));
  int b = bt >> 9;
  const float4* sp = (const float4*)(src + (size_t)bt * D_ + d0);
  const float4* tp = (const float4*)(tgt + ((size_t)(b * U_ + u)) * D_ + d0);
  float4 s0 = sp[0], s1 = sp[1], t0 = tp[0], t1 = tp[1];
  union { s16x8 v; unsigned short u16[8]; } r;
  r.u16[0] = f2bf(gelu_erf(s0.x + t0.x));
  r.u16[1] = f2bf(gelu_erf(s0.y + t0.y));
  r.u16[2] = f2bf(gelu_erf(s0.z + t0.z));
  r.u16[3] = f2bf(gelu_erf(s0.w + t0.w));
  r.u16[4] = f2bf(gelu_erf(s1.x + t1.x));
  r.u16[5] = f2bf(gelu_erf(s1.y + t1.y));
  r.u16[6] = f2bf(gelu_erf(s1.z + t1.z));
  r.u16[7] = f2bf(gelu_erf(s1.w + t1.w));
  *(s16x8*)(joint + e) = r.v;
}

// ---- stage 2: C[m,n] = sum_k A[m,k]*W[n,k] + bias[n] ----
// M=262144 (m-tile 128 == one (b,t), u=0..127), N=1024, K=512.
// FUSED=1: A computed in-staging (gelu), W converted in-staging; padded LDS.
// FUSED=0: A=joint bf16, B=Wbf via global_load_lds width-16 (unpadded).
template <int FUSED>
__global__ __launch_bounds__(256) void joiner_gemm(
    const unsigned short* __restrict__ joint, const unsigned short* __restrict__ Wbf,
    const float* __restrict__ src, const float* __restrict__ tgt,
    const float* __restrict__ Wf, const float* __restrict__ bias,
    float* __restrict__ out) {
  constexpr int PAD = FUSED ? 8 : 0;
  constexpr int LROW = 64 + PAD;  // elements per LDS row
  __shared__ unsigned short Asm[128 * LROW];
  __shared__ unsigned short Bsm[128 * LROW];

  const int bx = blockIdx.x;
  const int nt = bx & 7;    // n-tile fastest: 8 consecutive blocks share A-tile (LLC reuse)
  const int mt = bx >> 3;   // 0..2047 == b*T + t
  const int tid = threadIdx.x;
  const int wave = tid >> 6, lane = tid & 63;
  const int wm = wave >> 1, wn = wave & 1;
  const int quad = lane >> 4, l16 = lane & 15;
  const size_t m0 = (size_t)mt * 128;
  const int n0 = nt * 128;

  f32x4 acc[4][4] = {};

  for (int kk = 0; kk < 8; ++kk) {
    const int k0 = kk * 64;
    if constexpr (!FUSED) {
      #pragma unroll
      for (int i = 0; i < 4; ++i) {
        int chunk = wave * 4 + i;  // 1KB chunk = 8 rows of 128B
        const unsigned short* ga =
            joint + (m0 + (size_t)(chunk * 8 + (lane >> 3))) * D_ + k0 + (lane & 7) * 8;
        gload_lds16(ga, &Asm[chunk * 512]);
        const unsigned short* gb =
            Wbf + ((size_t)(n0 + chunk * 8 + (lane >> 3))) * D_ + k0 + (lane & 7) * 8;
        gload_lds16(gb, &Bsm[chunk * 512]);
      }
    } else {
      const int bb = mt >> 9;
      const float* srow = src + (size_t)mt * D_ + k0;
      #pragma unroll
      for (int i = 0; i < 4; ++i) {
        int unit = tid + i * 256;         // 1024 units: 128 rows x 8 k-chunks
        int row = unit >> 3, kc = unit & 7;
        const float4* tp = (const float4*)(tgt + ((size_t)(bb * U_ + row)) * D_ + k0 + kc * 8);
        const float4* sp = (const float4*)(srow + kc * 8);
        float4 t0v = tp[0], t1v = tp[1], s0v = sp[0], s1v = sp[1];
        union { s16x8 v; unsigned short u16[8]; } r;
        r.u16[0] = f2bf(gelu_tanh(s0v.x + t0v.x));
        r.u16[1] = f2bf(gelu_tanh(s0v.y + t0v.y));
        r.u16[2] = f2bf(gelu_tanh(s0v.z + t0v.z));
        r.u16[3] = f2bf(gelu_tanh(s0v.w + t0v.w));
        r.u16[4] = f2bf(gelu_tanh(s1v.x + t1v.x));
        r.u16[5] = f2bf(gelu_tanh(s1v.y + t1v.y));
        r.u16[6] = f2bf(gelu_tanh(s1v.z + t1v.z));
        r.u16[7] = f2bf(gelu_tanh(s1v.w + t1v.w));
        *(s16x8*)&Asm[row * LROW + kc * 8] = r.v;
        const float4* wp = (const float4*)(Wf + ((size_t)(n0 + row)) * D_ + k0 + kc * 8);
        float4 w0 = wp[0], w1 = wp[1];
        union { s16x8 v; unsigned short u16[8]; } rw;
        rw.u16[0] = f2bf(w0.x); rw.u16[1] = f2bf(w0.y);
        rw.u16[2] = f2bf(w0.z); rw.u16[3] = f2bf(w0.w);
        rw.u16[4] = f2bf(w1.x); rw.u16[5] = f2bf(w1.y);
        rw.u16[6] = f2bf(w1.z); rw.u16[7] = f2bf(w1.w);
        *(s16x8*)&Bsm[row * LROW + kc * 8] = rw.v;
      }
    }
    __syncthreads();
    #pragma unroll
    for (int ks = 0; ks < 2; ++ks) {
      s16x8 af[4], bf[4];
      #pragma unroll
      for (int mi = 0; mi < 4; ++mi)
        af[mi] = *(const s16x8*)&Asm[(wm * 64 + mi * 16 + l16) * LROW + ks * 32 + quad * 8];
      #pragma unroll
      for (int ni = 0; ni < 4; ++ni)
        bf[ni] = *(const s16x8*)&Bsm[(wn * 64 + ni * 16 + l16) * LROW + ks * 32 + quad * 8];
      #pragma unroll
      for (int mi = 0; mi < 4; ++mi)
        #pragma unroll
        for (int ni = 0; ni < 4; ++ni)
          acc[mi][ni] =
              __builtin_amdgcn_mfma_f32_16x16x32_bf16(af[mi], bf[ni], acc[mi][ni], 0, 0, 0);
    }
    __syncthreads();
  }

  // epilogue: C/D layout col=lane&15, row=quad*4+reg
  float bv[4];
  #pragma unroll
  for (int ni = 0; ni < 4; ++ni) bv[ni] = bias[n0 + wn * 64 + ni * 16 + l16];
  #pragma unroll
  for (int mi = 0; mi < 4; ++mi) {
    #pragma unroll
    for (int ni = 0; ni < 4; ++ni) {
      int n = n0 + wn * 64 + ni * 16 + l16;
      size_t mrow = m0 + wm * 64 + mi * 16 + quad * 4;
      #pragma unroll
      for (int r = 0; r < 4; ++r)
        out[(mrow + r) * V_ + n] = acc[mi][ni][r] + bv[ni];
    }
  }
}

extern "C" void kernel_launch(void* const* d_in, const int* in_sizes, int n_in,
                              void* d_out, int out_size, void* d_ws, size_t ws_size,
                              hipStream_t stream) {
  const float* src  = (const float*)d_in[0];
  const int*   sl   = (const int*)d_in[1];
  const float* tgt  = (const float*)d_in[2];
  const int*   tl   = (const int*)d_in[3];
  const float* W    = (const float*)d_in[4];
  const float* bias = (const float*)d_in[5];
  float* out = (float*)d_out;
  float* out_tail = out + OUT_MAIN;

  const size_t wbytes = (size_t)V_ * D_ * 2;            // 1 MiB (W bf16)
  const size_t jbytes = (size_t)B_ * T_ * U_ * D_ * 2;  // 256 MiB (joint bf16)
  const bool two_stage = ws_size >= wbytes + jbytes;

  if (two_stage) {
    unsigned short* Wbf = (unsigned short*)d_ws;
    unsigned short* joint = (unsigned short*)((char*)d_ws + wbytes);
    prep_kernel<<<256, 256, 0, stream>>>(W, sl, tl, out_tail, Wbf, 1);
    gelu_joint_kernel<<<65536, 256, 0, stream>>>(src, tgt, joint);
    joiner_gemm<0><<<16384, 256, 0, stream>>>(joint, Wbf, nullptr, nullptr, nullptr, bias, out);
  } else {
    prep_kernel<<<1, 256, 0, stream>>>(W, sl, tl, out_tail, nullptr, 0);
    joiner_gemm<1><<<16384, 256, 0, stream>>>(nullptr, nullptr, src, tgt, W, bias, out);
  }
}